// Round 1
// baseline (720.326 us; speedup 1.0000x reference)
//
#include <hip/hip_runtime.h>

#define N_IN   256
#define N_OUTC 128

typedef __attribute__((ext_vector_type(8))) short bf16x8;
typedef __attribute__((ext_vector_type(4))) float f32x4;

__device__ inline unsigned short f2bf(float f) {
    // round-to-nearest-even fp32 -> bf16
    unsigned u = __float_as_uint(f);
    unsigned r = u + 0x7fffu + ((u >> 16) & 1u);
    return (unsigned short)(r >> 16);
}

// ---------------- W fp32 [128,256] -> bf16 ----------------
__global__ void cvtW_kernel(const float* __restrict__ W, unsigned short* __restrict__ wb, int n) {
    int i = blockIdx.x * blockDim.x + threadIdx.x;
    if (i < n) wb[i] = f2bf(W[i]);
}

// ---------------- h = x @ W^T + b ----------------
// x [M,256] fp32 (converted to bf16 in-register), wb [128,256] bf16, h [M,128] fp32
// block = 256 (4 waves); each wave: 16 rows x 32 cols (2 MFMA 16x16x32 tiles); block covers 16 rows x 128 cols.
// Assumes M % 16 == 0 (M = 100000 = 16*6250).
__global__ __launch_bounds__(256) void gemm_h_kernel(const float* __restrict__ x,
                                                     const unsigned short* __restrict__ wb,
                                                     const float* __restrict__ b,
                                                     float* __restrict__ h, int M) {
    const int wave = threadIdx.x >> 6;
    const int lane = threadIdx.x & 63;
    const int quad = lane >> 4;
    const int l16  = lane & 15;
    const int m0   = blockIdx.x * 16;
    const int colbase = wave * 32;

    f32x4 acc0 = {0.f, 0.f, 0.f, 0.f};
    f32x4 acc1 = {0.f, 0.f, 0.f, 0.f};

    // A-frag source: x[m0+l16][kb + quad*8 + j], j=0..7 (A layout: m=lane&15, k=quad*8+j)
    const float* xrow = x + (size_t)(m0 + l16) * N_IN + quad * 8;
    // B-frag source: W[n][kb + quad*8 + j] with n = col (B layout: n=lane&15, k=quad*8+j)
    const unsigned short* w0 = wb + (size_t)(colbase + l16) * N_IN + quad * 8;
    const unsigned short* w1 = w0 + 16 * N_IN;

    #pragma unroll
    for (int kb = 0; kb < N_IN; kb += 32) {
        float4 a0 = *(const float4*)(xrow + kb);
        float4 a1 = *(const float4*)(xrow + kb + 4);
        bf16x8 af;
        af[0] = (short)f2bf(a0.x); af[1] = (short)f2bf(a0.y);
        af[2] = (short)f2bf(a0.z); af[3] = (short)f2bf(a0.w);
        af[4] = (short)f2bf(a1.x); af[5] = (short)f2bf(a1.y);
        af[6] = (short)f2bf(a1.z); af[7] = (short)f2bf(a1.w);
        bf16x8 bf0 = *(const bf16x8*)(w0 + kb);
        bf16x8 bf1 = *(const bf16x8*)(w1 + kb);
        acc0 = __builtin_amdgcn_mfma_f32_16x16x32_bf16(af, bf0, acc0, 0, 0, 0);
        acc1 = __builtin_amdgcn_mfma_f32_16x16x32_bf16(af, bf1, acc1, 0, 0, 0);
    }

    // C/D layout: row = quad*4 + reg, col = lane&15
    const int c0 = colbase + l16;
    const int c1 = c0 + 16;
    const float bv0 = b[c0];
    const float bv1 = b[c1];
    float* hp = h + (size_t)(m0 + quad * 4) * N_OUTC;
    #pragma unroll
    for (int r = 0; r < 4; r++) {
        hp[(size_t)r * N_OUTC + c0] = acc0[r] + bv0;
        hp[(size_t)r * N_OUTC + c1] = acc1[r] + bv1;
    }
}

// ---------------- bucket build (counting scatter) ----------------
__global__ void build_kernel(const int* __restrict__ rows, const int* __restrict__ cols,
                             const float* __restrict__ vals, int E,
                             int* __restrict__ counts, int2* __restrict__ bucket, int CAP) {
    int e = blockIdx.x * blockDim.x + threadIdx.x;
    if (e >= E) return;
    int r = rows[e];
    int pos = atomicAdd(&counts[r], 1);
    if (pos < CAP) bucket[(size_t)r * CAP + pos] = make_int2(cols[e], __float_as_int(vals[e]));
}

// ---------------- SpMM (wave per dst row) + concat epilogue ----------------
__global__ __launch_bounds__(256) void spmm_concat_kernel(const float* __restrict__ h,
                                                          const int* __restrict__ counts,
                                                          const int2* __restrict__ bucket, int CAP,
                                                          const int* __restrict__ prev,
                                                          float* __restrict__ out, int Ndst) {
    int r = blockIdx.x * 4 + (threadIdx.x >> 6);
    if (r >= Ndst) return;
    const int lane = threadIdx.x & 63;
    int cnt = counts[r];
    if (cnt > CAP) cnt = CAP;
    const int2* bk = bucket + (size_t)r * CAP;
    const float2* h2 = (const float2*)h;   // h row = 64 float2

    float2 acc = {0.f, 0.f};
    int e = 0;
    for (; e + 4 <= cnt; e += 4) {
        int2 cv0 = bk[e], cv1 = bk[e + 1], cv2 = bk[e + 2], cv3 = bk[e + 3];
        float2 g0 = h2[(size_t)cv0.x * 64 + lane];
        float2 g1 = h2[(size_t)cv1.x * 64 + lane];
        float2 g2 = h2[(size_t)cv2.x * 64 + lane];
        float2 g3 = h2[(size_t)cv3.x * 64 + lane];
        float v0 = __int_as_float(cv0.y), v1 = __int_as_float(cv1.y);
        float v2 = __int_as_float(cv2.y), v3 = __int_as_float(cv3.y);
        acc.x += v0 * g0.x; acc.y += v0 * g0.y;
        acc.x += v1 * g1.x; acc.y += v1 * g1.y;
        acc.x += v2 * g2.x; acc.y += v2 * g2.y;
        acc.x += v3 * g3.x; acc.y += v3 * g3.y;
    }
    for (; e < cnt; e++) {
        int2 cv = bk[e];
        float2 g = h2[(size_t)cv.x * 64 + lane];
        float v = __int_as_float(cv.y);
        acc.x += v * g.x; acc.y += v * g.y;
    }

    int p = prev[r];
    float2 hv = h2[(size_t)p * 64 + lane];
    float2* out2 = (float2*)out;           // out row = 128 float2
    out2[(size_t)r * 128 + lane]      = hv;   // cols [0,128)
    out2[(size_t)r * 128 + 64 + lane] = acc;  // cols [128,256)
}

// ---------------- fallback path (if ws too small for buckets) ----------------
__global__ void concat_only_kernel(const float* __restrict__ h, const int* __restrict__ prev,
                                   float* __restrict__ out, int Ndst) {
    int t = blockIdx.x * blockDim.x + threadIdx.x;
    int r = t >> 6, lane = t & 63;
    if (r >= Ndst) return;
    const float2* h2 = (const float2*)h;
    ((float2*)out)[(size_t)r * 128 + lane] = h2[(size_t)prev[r] * 64 + lane];
}

__global__ void spmm_atomic_kernel(const float* __restrict__ h, const int* __restrict__ rows,
                                   const int* __restrict__ cols, const float* __restrict__ vals,
                                   int E, float* __restrict__ out) {
    long long t = (long long)blockIdx.x * blockDim.x + threadIdx.x;
    int e = (int)(t >> 6), lane = (int)(t & 63);
    if (e >= E) return;
    int r = rows[e], c = cols[e];
    float v = vals[e];
    const float2* h2 = (const float2*)h;
    float2 g = h2[(size_t)c * 64 + lane];
    atomicAdd(&out[(size_t)r * 256 + 128 + 2 * lane], v * g.x);
    atomicAdd(&out[(size_t)r * 256 + 129 + 2 * lane], v * g.y);
}

extern "C" void kernel_launch(void* const* d_in, const int* in_sizes, int n_in,
                              void* d_out, int out_size, void* d_ws, size_t ws_size,
                              hipStream_t stream) {
    const float* x    = (const float*)d_in[0];
    const float* W    = (const float*)d_in[1];
    const float* b    = (const float*)d_in[2];
    const float* vals = (const float*)d_in[3];
    const int*   rows = (const int*)d_in[4];
    const int*   cols = (const int*)d_in[5];
    const int*   prev = (const int*)d_in[6];
    float* out = (float*)d_out;

    const int Nsrc = in_sizes[0] / N_IN;   // 100000
    const int E    = in_sizes[3];          // 3200000
    const int Ndst = in_sizes[6];          // 50000

    char* ws = (char*)d_ws;
    size_t off = 0;
    float* h = (float*)(ws + off);
    off += (size_t)Nsrc * N_OUTC * sizeof(float);              // 51.2 MB
    unsigned short* wb = (unsigned short*)(ws + off);
    off += (size_t)N_OUTC * N_IN * sizeof(unsigned short);     // 64 KB
    off = (off + 255) & ~(size_t)255;
    int* counts = (int*)(ws + off);
    off += (size_t)Ndst * sizeof(int);
    off = (off + 255) & ~(size_t)255;
    size_t bucketOff = off;

    // pick bucket capacity (avg degree 64; CAP>=128 keeps overflow prob ~1e-6, 192 is ~0)
    int CAP = 0;
    if (ws_size > bucketOff) {
        size_t per = (size_t)Ndst * sizeof(int2);
        int maxcap = (int)((ws_size - bucketOff) / per);
        if (maxcap >= 128) CAP = maxcap < 192 ? maxcap : 192;
    }

    cvtW_kernel<<<(N_OUTC * N_IN + 255) / 256, 256, 0, stream>>>(W, wb, N_OUTC * N_IN);
    gemm_h_kernel<<<Nsrc / 16, 256, 0, stream>>>(x, wb, b, h, Nsrc);

    if (CAP > 0) {
        hipMemsetAsync(counts, 0, (size_t)Ndst * sizeof(int), stream);
        int2* bucket = (int2*)(ws + bucketOff);
        build_kernel<<<(E + 255) / 256, 256, 0, stream>>>(rows, cols, vals, E, counts, bucket, CAP);
        spmm_concat_kernel<<<(Ndst + 3) / 4, 256, 0, stream>>>(h, counts, bucket, CAP, prev, out, Ndst);
    } else {
        hipMemsetAsync(out, 0, (size_t)out_size * sizeof(float), stream);
        concat_only_kernel<<<((size_t)Ndst * 64 + 255) / 256, 256, 0, stream>>>(h, prev, out, Ndst);
        spmm_atomic_kernel<<<((size_t)E * 64 + 255) / 256, 256, 0, stream>>>(h, rows, cols, vals, E, out);
    }
}